// Round 6
// baseline (200.410 us; speedup 1.0000x reference)
//
#include <hip/hip_runtime.h>
#include <math.h>

#define NB 32
#define HQ 16
#define DN 128
#define DR 64
#define DQ (DN + DR)
#define DV 128
#define PAGE 64
#define MAXP 64
#define SM_SCALE 0.07216878364870322f

typedef __attribute__((ext_vector_type(8))) _Float16 f16x8;
typedef __attribute__((ext_vector_type(4))) _Float16 f16x4;
typedef __attribute__((ext_vector_type(2))) __fp16   h16x2;  // cvt_pkrtz result type
typedef __attribute__((ext_vector_type(4))) float    f32x4;

union F16x8 { f16x8 v; h16x2 h[4]; };
union F16x4 { f16x4 v; h16x2 h[2]; };

// Intra-wave LDS ordering (DS ops are in-order per wave; stop compiler reorder).
#define WAVE_LDS_FENCE() asm volatile("s_waitcnt lgkmcnt(0)" ::: "memory")

// One BLOCK = one WAVE = (batch b, chunk c). A chunk is MT*16 tokens inside a
// single page (MT=2: half page -> NS=128 chunks/batch). Straight-line: all
// loads independent, single-pass softmax (no online state), then PV.
// Scores: mfma_f32_16x16x32_f16, A=K-tile(16 tok x 32 d), B=q^T (wave-resident,
// 24 VGPRs). PV: A=V^T frag (scalar-gathered), B=P via LDS round-trip.
// Lane roles: ln=lane&15, qd=lane>>4.
template<int MT>   // 16-token tiles per chunk (2 or 4)
__global__ __launch_bounds__(64, 1)
void attn_partial_kernel(const float* __restrict__ q,
                         const float* __restrict__ kn,
                         const float* __restrict__ kr,
                         const float* __restrict__ v,
                         const int* __restrict__ seq_lens,
                         const int* __restrict__ block_table,
                         float* __restrict__ o_part,   // [NB][NS][HQ][DV]
                         float* __restrict__ ml_part)  // [NB][NS][HQ][2]
{
    constexpr int NS  = (MAXP * PAGE) / (MT * 16);  // chunks per batch
    constexpr int PRS = MT * 16 + 8;                // P row stride (f16), 16B-aligned rows

    const int lane = (int)threadIdx.x;
    const int ln   = lane & 15;
    const int qd   = lane >> 4;

    const int b = blockIdx.x / NS;
    const int c = blockIdx.x % NS;
    const int tok0 = c * (MT * 16);

    const int seq = seq_lens[b];
    if (tok0 >= seq) return;                 // whole-block exit; scheduler backfills

    const int page    = tok0 / PAGE;         // chunk never crosses a page (MT<=4)
    const int in_page = tok0 % PAGE;
    const int pid = block_table[b * MAXP + page];

    __shared__ _Float16 p_s[HQ][PRS];        // wave-private P buffer

    const float* knb = kn + (size_t)pid * PAGE * DN;
    const float* krb = kr + (size_t)pid * PAGE * DR;
    const float* vb  = v  + (size_t)pid * PAGE * DV;

    // q B-frags: bq[kt] element j = q[b][h=ln][kt*32 + qd*8 + j]
    F16x8 bq[6];
    {
        const float* qrow = q + ((size_t)b * HQ + ln) * DQ + qd * 8;
        #pragma unroll
        for (int kt = 0; kt < 6; kt++) {
            float4 x0 = *(const float4*)(qrow + kt * 32);
            float4 x1 = *(const float4*)(qrow + kt * 32 + 4);
            bq[kt].h[0] = __builtin_amdgcn_cvt_pkrtz(x0.x, x0.y);
            bq[kt].h[1] = __builtin_amdgcn_cvt_pkrtz(x0.z, x0.w);
            bq[kt].h[2] = __builtin_amdgcn_cvt_pkrtz(x1.x, x1.y);
            bq[kt].h[3] = __builtin_amdgcn_cvt_pkrtz(x1.z, x1.w);
        }
    }

    // ---- V prefetch (independent of score chain; issues up front) ----
    // vraw[kt2*8+mt2][j] = V[in_page + kt2*32 + qd*8 + j][mt2*16 + ln]
    float vraw[MT / 2 * 8][8];
    #pragma unroll
    for (int kt2 = 0; kt2 < MT / 2; kt2++) {
        const int t0 = in_page + kt2 * 32 + qd * 8;
        #pragma unroll
        for (int mt2 = 0; mt2 < 8; mt2++) {
            const float* vc = vb + mt2 * 16 + ln;
            #pragma unroll
            for (int j = 0; j < 8; j++)
                vraw[kt2 * 8 + mt2][j] = vc[(size_t)(t0 + j) * DV];
        }
    }

    // ---- scores: S[tok][head], MT token-tiles x 6 k-tiles ----
    f32x4 sc[MT];
    #pragma unroll
    for (int mt = 0; mt < MT; mt++) sc[mt] = (f32x4){0.f, 0.f, 0.f, 0.f};
    #pragma unroll
    for (int mt = 0; mt < MT; mt++) {
        const float* rn = knb + (size_t)(in_page + mt * 16 + ln) * DN + qd * 8;
        const float* rr = krb + (size_t)(in_page + mt * 16 + ln) * DR + qd * 8;
        #pragma unroll
        for (int kt = 0; kt < 6; kt++) {
            const float* src = (kt < 4) ? (rn + kt * 32) : (rr + (kt - 4) * 32);
            float4 x0 = *(const float4*)(src);
            float4 x1 = *(const float4*)(src + 4);
            F16x8 a;
            a.h[0] = __builtin_amdgcn_cvt_pkrtz(x0.x, x0.y);
            a.h[1] = __builtin_amdgcn_cvt_pkrtz(x0.z, x0.w);
            a.h[2] = __builtin_amdgcn_cvt_pkrtz(x1.x, x1.y);
            a.h[3] = __builtin_amdgcn_cvt_pkrtz(x1.z, x1.w);
            sc[mt] = __builtin_amdgcn_mfma_f32_16x16x32_f16(a.v, bq[kt].v, sc[mt], 0, 0, 0);
        }
    }

    // ---- single-pass softmax (state for head ln replicated on 4 lanes) ----
    float sv[MT][4];
    float smax = -INFINITY;
    #pragma unroll
    for (int mt = 0; mt < MT; mt++)
        #pragma unroll
        for (int r = 0; r < 4; r++) {
            int tok = tok0 + mt * 16 + qd * 4 + r;
            float x = (tok < seq) ? sc[mt][r] * SM_SCALE : -INFINITY;
            sv[mt][r] = x;
            smax = fmaxf(smax, x);
        }
    smax = fmaxf(smax, __shfl_xor(smax, 16));
    smax = fmaxf(smax, __shfl_xor(smax, 32));   // finite: >=1 valid token per chunk
    float lsum = 0.f;
    #pragma unroll
    for (int mt = 0; mt < MT; mt++)
        #pragma unroll
        for (int r = 0; r < 4; r++) {
            float e = __expf(sv[mt][r] - smax);
            sv[mt][r] = e;
            lsum += e;
        }
    lsum += __shfl_xor(lsum, 16);
    lsum += __shfl_xor(lsum, 32);

    // ---- P -> LDS rows [head][token] (f16) ----
    #pragma unroll
    for (int mt = 0; mt < MT; mt++) {
        F16x4 w;
        w.h[0] = __builtin_amdgcn_cvt_pkrtz(sv[mt][0], sv[mt][1]);
        w.h[1] = __builtin_amdgcn_cvt_pkrtz(sv[mt][2], sv[mt][3]);
        *(f16x4*)(&p_s[ln][mt * 16 + qd * 4]) = w.v;
    }
    WAVE_LDS_FENCE();                        // RAW before frag reads

    // ---- PV: O^T[dv][head] += V^T . P ----
    f32x4 o_acc[8];
    #pragma unroll
    for (int i = 0; i < 8; i++) o_acc[i] = (f32x4){0.f, 0.f, 0.f, 0.f};
    #pragma unroll
    for (int kt2 = 0; kt2 < MT / 2; kt2++) {
        f16x8 pf = *(const f16x8*)(&p_s[ln][kt2 * 32 + qd * 8]);
        #pragma unroll
        for (int mt2 = 0; mt2 < 8; mt2++) {
            const float* vr = vraw[kt2 * 8 + mt2];
            F16x8 a;
            a.h[0] = __builtin_amdgcn_cvt_pkrtz(vr[0], vr[1]);
            a.h[1] = __builtin_amdgcn_cvt_pkrtz(vr[2], vr[3]);
            a.h[2] = __builtin_amdgcn_cvt_pkrtz(vr[4], vr[5]);
            a.h[3] = __builtin_amdgcn_cvt_pkrtz(vr[6], vr[7]);
            o_acc[mt2] = __builtin_amdgcn_mfma_f32_16x16x32_f16(a.v, pf, o_acc[mt2], 0, 0, 0);
        }
    }

    // ---- epilogue: unnormalized partials ----
    float* op = o_part + ((size_t)(b * NS + c) * HQ + ln) * DV + qd * 4;
    #pragma unroll
    for (int mt2 = 0; mt2 < 8; mt2++)
        *(f32x4*)(op + mt2 * 16) = o_acc[mt2];
    if (qd == 0) {
        float2* ml = (float2*)(ml_part) + (size_t)(b * NS + c) * HQ + ln;
        *ml = make_float2(smax, lsum);
    }
}

// LSE merge across chunks: pass 1 max, pass 2 weighted sum.
template<int MT>
__global__ __launch_bounds__(128)
void attn_combine_kernel(const float* __restrict__ o_part,
                         const float* __restrict__ ml_part,
                         const int* __restrict__ seq_lens,
                         float* __restrict__ out)
{
    constexpr int NS  = (MAXP * PAGE) / (MT * 16);
    constexpr int TPC = MT * 16;
    const int h = blockIdx.x;
    const int b = blockIdx.y;
    const int d = (int)threadIdx.x;
    const int seq = seq_lens[b];
    int ns = (seq + TPC - 1) / TPC;
    if (ns > NS) ns = NS;

    const float2* mlb = (const float2*)(ml_part) + (size_t)b * NS * HQ + h;
    float M = -INFINITY;
    #pragma unroll 8
    for (int s2 = 0; s2 < ns; s2++)
        M = fmaxf(M, mlb[(size_t)s2 * HQ].x);

    float acc = 0.f, den = 0.f;
    #pragma unroll 4
    for (int s2 = 0; s2 < ns; s2++) {
        float2 ml = mlb[(size_t)s2 * HQ];
        float e = __expf(ml.x - M);
        float o = o_part[((size_t)(b * NS + s2) * HQ + h) * DV + d];
        acc += e * o;
        den += e * ml.y;
    }
    out[((size_t)b * HQ + h) * DV + d] = acc / den;
}

template<int MT>
static void launch_all(const float* q, const float* kn, const float* kr,
                       const float* v, const int* seq_lens, const int* block_table,
                       float* d_ws, float* d_out, hipStream_t stream)
{
    constexpr int NS = (MAXP * PAGE) / (MT * 16);
    float* o_part  = d_ws;
    float* ml_part = o_part + (size_t)NB * NS * HQ * DV;
    attn_partial_kernel<MT><<<NB * NS, 64, 0, stream>>>(
        q, kn, kr, v, seq_lens, block_table, o_part, ml_part);
    attn_combine_kernel<MT><<<dim3(HQ, NB), 128, 0, stream>>>(
        o_part, ml_part, seq_lens, d_out);
}

extern "C" void kernel_launch(void* const* d_in, const int* in_sizes, int n_in,
                              void* d_out, int out_size, void* d_ws, size_t ws_size,
                              hipStream_t stream)
{
    const float* q  = (const float*)d_in[0];
    const float* kn = (const float*)d_in[1];
    const float* kr = (const float*)d_in[2];
    const float* v  = (const float*)d_in[3];
    const int* seq_lens    = (const int*)d_in[4];
    const int* block_table = (const int*)d_in[5];

    const size_t need128 = (size_t)NB * 128 * HQ * (DV + 2) * 4;  // ~34.1 MB
    if (ws_size >= need128)
        launch_all<2>(q, kn, kr, v, seq_lens, block_table, (float*)d_ws, (float*)d_out, stream);
    else
        launch_all<4>(q, kn, kr, v, seq_lens, block_table, (float*)d_ws, (float*)d_out, stream);
}

// Round 7
// 185.131 us; speedup vs baseline: 1.0825x; 1.0825x over previous
//
#include <hip/hip_runtime.h>
#include <math.h>

#define NB 32
#define HQ 16
#define DN 128
#define DR 64
#define DQ (DN + DR)
#define DV 128
#define PAGE 64
#define MAXP 64
#define SM_SCALE 0.07216878364870322f
#define RS 72   // p_s row stride (f16): 144 B -> 16B-aligned frags, 2-way bank alias (free)

typedef __attribute__((ext_vector_type(8))) _Float16 f16x8;
typedef __attribute__((ext_vector_type(4))) _Float16 f16x4;
typedef __attribute__((ext_vector_type(2))) __fp16   h16x2;  // cvt_pkrtz result type
typedef __attribute__((ext_vector_type(4))) float    f32x4;

union F16x8 { f16x8 v; h16x2 h[4]; };
union F16x4 { f16x4 v; h16x2 h[2]; };

// Loads cannot sink past a memory clobber: pins issue order, forces the
// allocator to materialize in-flight load destinations (R5/R6 failure mode:
// compiler sank "prefetch" loads to uses -> VGPR_Count 60, serial waits).
#define SCHED_PIN()      asm volatile("" ::: "memory")
#define WAVE_LDS_FENCE() asm volatile("s_waitcnt lgkmcnt(0)" ::: "memory")

// ---- phase helpers (all fully unrolled, constant indices -> registers) ----

static __device__ __forceinline__ void issue_k_band(
    const float* knb, const float* krb, int mtbase, int ln, int qd, float4* kb)
{
    #pragma unroll
    for (int m = 0; m < 2; m++) {
        const int mt = mtbase + m;
        const float* rn = knb + (size_t)(mt * 16 + ln) * DN + qd * 8;
        const float* rr = krb + (size_t)(mt * 16 + ln) * DR + qd * 8;
        #pragma unroll
        for (int kt = 0; kt < 4; kt++) {
            kb[m * 12 + kt * 2]     = *(const float4*)(rn + kt * 32);
            kb[m * 12 + kt * 2 + 1] = *(const float4*)(rn + kt * 32 + 4);
        }
        kb[m * 12 + 8]  = *(const float4*)(rr);
        kb[m * 12 + 9]  = *(const float4*)(rr + 4);
        kb[m * 12 + 10] = *(const float4*)(rr + 32);
        kb[m * 12 + 11] = *(const float4*)(rr + 36);
    }
}

static __device__ __forceinline__ void issue_v_band(
    const float* vb, int kt2, int ln, int qd, float vr[8][8])
{
    const int t0 = kt2 * 32 + qd * 8;
    #pragma unroll
    for (int mt2 = 0; mt2 < 8; mt2++) {
        const float* vc = vb + mt2 * 16 + ln;
        #pragma unroll
        for (int j = 0; j < 8; j++)
            vr[mt2][j] = vc[(size_t)(t0 + j) * DV];
    }
}

static __device__ __forceinline__ void score_band(
    const float4* kb, const F16x8* bq, int mtbase, f32x4* sc)
{
    #pragma unroll
    for (int m = 0; m < 2; m++)
        #pragma unroll
        for (int kt = 0; kt < 6; kt++) {
            float4 x0 = kb[m * 12 + kt * 2];
            float4 x1 = kb[m * 12 + kt * 2 + 1];
            F16x8 a;
            a.h[0] = __builtin_amdgcn_cvt_pkrtz(x0.x, x0.y);
            a.h[1] = __builtin_amdgcn_cvt_pkrtz(x0.z, x0.w);
            a.h[2] = __builtin_amdgcn_cvt_pkrtz(x1.x, x1.y);
            a.h[3] = __builtin_amdgcn_cvt_pkrtz(x1.z, x1.w);
            sc[mtbase + m] = __builtin_amdgcn_mfma_f32_16x16x32_f16(
                a.v, bq[kt].v, sc[mtbase + m], 0, 0, 0);
        }
}

static __device__ __forceinline__ void pv_band(
    const float vr[8][8], f16x8 pf, f32x4* o_acc)
{
    #pragma unroll
    for (int mt2 = 0; mt2 < 8; mt2++) {
        F16x8 a;
        a.h[0] = __builtin_amdgcn_cvt_pkrtz(vr[mt2][0], vr[mt2][1]);
        a.h[1] = __builtin_amdgcn_cvt_pkrtz(vr[mt2][2], vr[mt2][3]);
        a.h[2] = __builtin_amdgcn_cvt_pkrtz(vr[mt2][4], vr[mt2][5]);
        a.h[3] = __builtin_amdgcn_cvt_pkrtz(vr[mt2][6], vr[mt2][7]);
        o_acc[mt2] = __builtin_amdgcn_mfma_f32_16x16x32_f16(a.v, pf, o_acc[mt2], 0, 0, 0);
    }
}

// One BLOCK = one WAVE = (batch b, chunk of PPC pages). Scores:
// mfma_f32_16x16x32_f16, A=K-tile(16 tok x 32 d), B=q^T (wave-resident 24
// VGPRs). PV: A=V^T (register gather), B=P (wave-private LDS round-trip).
// Lane roles: ln=lane&15, qd=lane>>4. launch_bounds(64,1): VGPR cap 512;
// target ~230 VGPR -> 2 waves/SIMD with all of a page's loads in flight.
template<int PPC>
__global__ __launch_bounds__(64, 1)
void attn_partial_kernel(const float* __restrict__ q,
                         const float* __restrict__ kn,
                         const float* __restrict__ kr,
                         const float* __restrict__ v,
                         const int* __restrict__ seq_lens,
                         const int* __restrict__ block_table,
                         float* __restrict__ o_part,   // [NB][NSC][HQ][DV]
                         float* __restrict__ ml_part)  // [NB][NSC][HQ][2]
{
    constexpr int NSC = MAXP / PPC;
    const int lane = (int)threadIdx.x;
    const int ln   = lane & 15;
    const int qd   = lane >> 4;

    const int b = blockIdx.x / NSC;
    const int c = blockIdx.x % NSC;

    const int seq = seq_lens[b];                    // s_load
    int pid = block_table[b * MAXP + c * PPC];      // s_load, same wait
    if (c * PPC * PAGE >= seq) return;              // whole-block exit

    __shared__ _Float16 p_s[HQ][RS];                // wave-private P buffer

    // q loads issued up front (12 dwordx4); converted to frags after pin #1
    float4 qraw[12];
    {
        const float* qrow = q + ((size_t)b * HQ + ln) * DQ + qd * 8;
        #pragma unroll
        for (int kt = 0; kt < 6; kt++) {
            qraw[2 * kt]     = *(const float4*)(qrow + kt * 32);
            qraw[2 * kt + 1] = *(const float4*)(qrow + kt * 32 + 4);
        }
    }

    F16x8 bq[6];
    float m_run = -INFINITY, l_run = 0.f;
    f32x4 o_acc[8];
    #pragma unroll
    for (int i = 0; i < 8; i++) o_acc[i] = (f32x4){0.f, 0.f, 0.f, 0.f};

    #pragma unroll
    for (int pg = 0; pg < PPC; pg++) {
        const int page = c * PPC + pg;
        if (page * PAGE >= seq) break;              // wave-uniform
        if (pg > 0) pid = block_table[b * MAXP + page];

        const float* knb = kn + (size_t)pid * PAGE * DN;
        const float* krb = kr + (size_t)pid * PAGE * DR;
        const float* vb  = v  + (size_t)pid * PAGE * DV;

        float4 kb0[24], kb1[24];
        float  va[8][8], vbr[8][8];

        // ---- issue wave 1: K band0 (96 VGPR) + V band0 (64) + q (48) ----
        issue_k_band(knb, krb, 0, ln, qd, kb0);
        issue_v_band(vb, 0, ln, qd, va);
        SCHED_PIN();

        // q frags: bq[kt][j] = q[b][h=ln][kt*32 + qd*8 + j]   (page 0 only)
        if (pg == 0) {
            #pragma unroll
            for (int kt = 0; kt < 6; kt++) {
                float4 x0 = qraw[2 * kt], x1 = qraw[2 * kt + 1];
                bq[kt].h[0] = __builtin_amdgcn_cvt_pkrtz(x0.x, x0.y);
                bq[kt].h[1] = __builtin_amdgcn_cvt_pkrtz(x0.z, x0.w);
                bq[kt].h[2] = __builtin_amdgcn_cvt_pkrtz(x1.x, x1.y);
                bq[kt].h[3] = __builtin_amdgcn_cvt_pkrtz(x1.z, x1.w);
            }
        }

        f32x4 sc[4];
        #pragma unroll
        for (int mt = 0; mt < 4; mt++) sc[mt] = (f32x4){0.f, 0.f, 0.f, 0.f};

        score_band(kb0, bq, 0, sc);                 // consumes kb0

        issue_k_band(knb, krb, 2, ln, qd, kb1);     // issue wave 2 (kb0 freed)
        SCHED_PIN();
        score_band(kb1, bq, 2, sc);

        issue_v_band(vb, 1, ln, qd, vbr);           // issue wave 3
        SCHED_PIN();

        // ---- online softmax (head ln state replicated on 4 lanes) ----
        float sv[4][4];
        float smax = -INFINITY;
        #pragma unroll
        for (int mt = 0; mt < 4; mt++)
            #pragma unroll
            for (int r = 0; r < 4; r++) {
                int tok = page * PAGE + mt * 16 + qd * 4 + r;
                float x = (tok < seq) ? sc[mt][r] * SM_SCALE : -INFINITY;
                sv[mt][r] = x;
                smax = fmaxf(smax, x);
            }
        smax = fmaxf(smax, __shfl_xor(smax, 16));
        smax = fmaxf(smax, __shfl_xor(smax, 32));
        const float m_new = fmaxf(m_run, smax);
        const float alpha = __expf(m_run - m_new);  // first page: exp(-inf)=0
        m_run = m_new;
        float lsum = 0.f;
        #pragma unroll
        for (int mt = 0; mt < 4; mt++)
            #pragma unroll
            for (int r = 0; r < 4; r++) {
                float e = __expf(sv[mt][r] - m_new);
                sv[mt][r] = e;
                lsum += e;
            }
        lsum += __shfl_xor(lsum, 16);
        lsum += __shfl_xor(lsum, 32);
        l_run = l_run * alpha + lsum;

        // ---- P -> LDS rows [head][token] (f16); DS in-order per wave ----
        WAVE_LDS_FENCE();                           // WAR vs prev page's reads
        #pragma unroll
        for (int mt = 0; mt < 4; mt++) {
            F16x4 w;
            w.h[0] = __builtin_amdgcn_cvt_pkrtz(sv[mt][0], sv[mt][1]);
            w.h[1] = __builtin_amdgcn_cvt_pkrtz(sv[mt][2], sv[mt][3]);
            *(f16x4*)(&p_s[ln][mt * 16 + qd * 4]) = w.v;
        }
        WAVE_LDS_FENCE();                           // RAW before frag reads

        #pragma unroll
        for (int i = 0; i < 8; i++) o_acc[i] *= alpha;

        // ---- PV: O^T[dv][head] += V^T . P ----
        {
            f16x8 pf0 = *(const f16x8*)(&p_s[ln][qd * 8]);
            pv_band(va, pf0, o_acc);
            f16x8 pf1 = *(const f16x8*)(&p_s[ln][32 + qd * 8]);
            pv_band(vbr, pf1, o_acc);
        }
    }

    // ---- epilogue: unnormalized partials ----
    float* op = o_part + ((size_t)(b * NSC + c) * HQ + ln) * DV + qd * 4;
    #pragma unroll
    for (int mt2 = 0; mt2 < 8; mt2++)
        *(f32x4*)(op + mt2 * 16) = o_acc[mt2];
    if (qd == 0) {
        float2* ml = (float2*)(ml_part) + (size_t)(b * NSC + c) * HQ + ln;
        *ml = make_float2(m_run, l_run);
    }
}

// LSE merge across chunks: pass 1 max, pass 2 weighted sum.
template<int PPC>
__global__ __launch_bounds__(128)
void attn_combine_kernel(const float* __restrict__ o_part,
                         const float* __restrict__ ml_part,
                         const int* __restrict__ seq_lens,
                         float* __restrict__ out)
{
    constexpr int NSC = MAXP / PPC;
    constexpr int TPC = PPC * PAGE;
    const int h = blockIdx.x;
    const int b = blockIdx.y;
    const int d = (int)threadIdx.x;
    const int seq = seq_lens[b];
    int ns = (seq + TPC - 1) / TPC;
    if (ns > NSC) ns = NSC;

    const float2* mlb = (const float2*)(ml_part) + (size_t)b * NSC * HQ + h;
    float M = -INFINITY;
    #pragma unroll 8
    for (int s2 = 0; s2 < ns; s2++)
        M = fmaxf(M, mlb[(size_t)s2 * HQ].x);

    float acc = 0.f, den = 0.f;
    #pragma unroll 4
    for (int s2 = 0; s2 < ns; s2++) {
        float2 ml = mlb[(size_t)s2 * HQ];
        float e = __expf(ml.x - M);
        float o = o_part[((size_t)(b * NSC + s2) * HQ + h) * DV + d];
        acc += e * o;
        den += e * ml.y;
    }
    out[((size_t)b * HQ + h) * DV + d] = acc / den;
}

template<int PPC>
static void launch_all(const float* q, const float* kn, const float* kr,
                       const float* v, const int* seq_lens, const int* block_table,
                       float* d_ws, float* d_out, hipStream_t stream)
{
    constexpr int NSC = MAXP / PPC;
    float* o_part  = d_ws;
    float* ml_part = o_part + (size_t)NB * NSC * HQ * DV;
    attn_partial_kernel<PPC><<<NB * NSC, 64, 0, stream>>>(
        q, kn, kr, v, seq_lens, block_table, o_part, ml_part);
    attn_combine_kernel<PPC><<<dim3(HQ, NB), 128, 0, stream>>>(
        o_part, ml_part, seq_lens, d_out);
}

extern "C" void kernel_launch(void* const* d_in, const int* in_sizes, int n_in,
                              void* d_out, int out_size, void* d_ws, size_t ws_size,
                              hipStream_t stream)
{
    const float* q  = (const float*)d_in[0];
    const float* kn = (const float*)d_in[1];
    const float* kr = (const float*)d_in[2];
    const float* v  = (const float*)d_in[3];
    const int* seq_lens    = (const int*)d_in[4];
    const int* block_table = (const int*)d_in[5];

    const size_t need1 = (size_t)NB * 64 * HQ * (DV + 2) * 4;   // ~17.0 MB
    const size_t need2 = (size_t)NB * 32 * HQ * (DV + 2) * 4;   // ~8.5 MB

    if (ws_size >= need1)
        launch_all<1>(q, kn, kr, v, seq_lens, block_table, (float*)d_ws, (float*)d_out, stream);
    else if (ws_size >= need2)
        launch_all<2>(q, kn, kr, v, seq_lens, block_table, (float*)d_ws, (float*)d_out, stream);
    else
        launch_all<4>(q, kn, kr, v, seq_lens, block_table, (float*)d_ws, (float*)d_out, stream);
}